// Round 7
// baseline (5030.311 us; speedup 1.0000x reference)
//
#include <hip/hip_runtime.h>
#include <math.h>

// B=8, C=128, H=128, W=128, D_INNER=256, D_STATE=64, HEADDIM=32, NHEADS=8,
// D_CONV=4, GN_GROUPS=8, D_XBC=384, D_INPROJ=648.
// Inputs f32 (probed via gn_g word0). OUTPUT IS F32 (reference output dtype).
// d_out = [out_2d: 16,777,216 f32][offset: 131,072 f32].
// h1 (f32) is staged in d_out's out_2d region (written by dwconv, read by gn_off,
// later fully overwritten by gemm2).

__device__ __forceinline__ float b2f(unsigned short u) {
  return __uint_as_float(((unsigned int)u) << 16);
}
__device__ __forceinline__ unsigned short f2b(float f) {
  unsigned int u = __float_as_uint(f);
  unsigned int r = (u + 0x7FFFu + ((u >> 16) & 1u)) >> 16;  // RNE
  return (unsigned short)r;
}
__device__ __forceinline__ bool in_is_f32(const void* gng) {
  return ((const unsigned int*)gng)[0] == 0x3F800000u;
}

#define P_DWW 0
#define P_CW 3200
#define P_CB 4736
#define P_GNG 5120
#define P_GNB 5248
#define P_PWW 5376
#define P_PWB 5504
#define P_DTB 5505
#define P_ALOG 5513
#define P_DSKIP 5521
#define P_NG 5529

__global__ void k_prep_params(const void* dww, const void* cw, const void* cb,
                              const void* gng, const void* gnb, const void* pww,
                              const void* pwb, const void* dtbias, const void* alog,
                              const void* dskip, const void* ng, float* __restrict__ P,
                              float* __restrict__ gst) {
  bool f = in_is_f32(gng);
  int tid = threadIdx.x;
  if (tid < 128) gst[tid] = 0.f;
  auto cvt = [&](const void* src, int n, int off) {
    for (int i = tid; i < n; i += 256)
      P[off + i] = f ? ((const float*)src)[i] : b2f(((const unsigned short*)src)[i]);
  };
  cvt(dww, 3200, P_DWW);
  cvt(cw, 1536, P_CW);
  cvt(cb, 384, P_CB);
  cvt(gng, 128, P_GNG);
  cvt(gnb, 128, P_GNB);
  cvt(pww, 128, P_PWW);
  cvt(pwb, 1, P_PWB);
  cvt(dtbias, 8, P_DTB);
  cvt(alog, 8, P_ALOG);
  cvt(dskip, 8, P_DSKIP);
  cvt(ng, 256, P_NG);
}

__global__ void k_prep_w(const void* wproj, const void* outw, const void* gng,
                         float* __restrict__ wprojf, float* __restrict__ outwf) {
  bool f = in_is_f32(gng);
  int stride = gridDim.x * blockDim.x;
  for (int i = blockIdx.x * blockDim.x + threadIdx.x; i < 82944; i += stride)
    wprojf[i] = f ? ((const float*)wproj)[i] : b2f(((const unsigned short*)wproj)[i]);
  for (int i = blockIdx.x * blockDim.x + threadIdx.x; i < 32768; i += stride)
    outwf[i] = f ? ((const float*)outw)[i] : b2f(((const unsigned short*)outw)[i]);
}

// ---------------- K1: depthwise 5x5 conv (SAME, zero pad) + group stats ----------
// x staged in LDS as bf16 (f32 tile would exceed 64KB static LDS); h1 out f32.
__global__ __launch_bounds__(256) void k_dwconv(const void* __restrict__ x,
                                                const void* __restrict__ gng,
                                                const float* __restrict__ P,
                                                float* __restrict__ h1,
                                                float* __restrict__ gst) {
  int bc = blockIdx.x;
  int b = bc >> 7, c = bc & 127;
  bool f32x = in_is_f32(gng);
  __shared__ unsigned short t[132 * 132];
  __shared__ float red[8];
  for (int i = threadIdx.x; i < 132 * 132; i += 256) t[i] = 0;
  __syncthreads();
  const float* xf = (const float*)x + (size_t)bc * 16384;
  const unsigned short* xb = (const unsigned short*)x + (size_t)bc * 16384;
  for (int i = threadIdx.x; i < 16384; i += 256) {
    int y = i >> 7, xw = i & 127;
    t[(y + 2) * 132 + xw + 2] = f32x ? f2b(xf[i]) : xb[i];
  }
  float w[25];
#pragma unroll
  for (int k = 0; k < 25; ++k) w[k] = P[P_DWW + c * 25 + k];
  __syncthreads();
  float s = 0.f, sq = 0.f;
  for (int i = threadIdx.x; i < 16384; i += 256) {
    int y = i >> 7, xw = i & 127;
    float acc = 0.f;
#pragma unroll
    for (int ky = 0; ky < 5; ++ky)
#pragma unroll
      for (int kx = 0; kx < 5; ++kx)
        acc += w[ky * 5 + kx] * b2f(t[(y + ky) * 132 + xw + kx]);
    h1[(size_t)bc * 16384 + i] = acc;
    s += acc; sq += acc * acc;
  }
  for (int o = 32; o; o >>= 1) { s += __shfl_down(s, o, 64); sq += __shfl_down(sq, o, 64); }
  int wv = threadIdx.x >> 6;
  if ((threadIdx.x & 63) == 0) { red[wv] = s; red[4 + wv] = sq; }
  __syncthreads();
  if (threadIdx.x == 0) {
    float ts = red[0] + red[1] + red[2] + red[3];
    float tq = red[4] + red[5] + red[6] + red[7];
    int g = (b << 3) + (c >> 4);
    atomicAdd(&gst[g * 2], ts);
    atomicAdd(&gst[g * 2 + 1], tq);
  }
}

__global__ void k_stats(const float* __restrict__ gst, float* __restrict__ mr) {
  int g = threadIdx.x;
  if (g < 64) {
    const float invN = 1.f / 262144.f;
    float mean = gst[g * 2] * invN;
    float var = gst[g * 2 + 1] * invN - mean * mean;
    mr[g * 2] = mean;
    mr[g * 2 + 1] = rsqrtf(var + 1e-5f);
  }
}

// ---------------- K3: GN + exact GELU + 1x1 conv + tanh*8 -> offset (f32 out) ----
__global__ __launch_bounds__(128) void k_gn_off(const float* __restrict__ h1,
                                                const float* __restrict__ mr,
                                                const float* __restrict__ P,
                                                float* __restrict__ offf,
                                                float* __restrict__ dout) {
  int bh = blockIdx.x;
  int b = bh >> 7, h = bh & 127;
  int w = threadIdx.x;
  float acc = 0.f;
  for (int c = 0; c < 128; ++c) {
    float v = h1[(((size_t)(b * 128 + c)) * 128 + h) * 128 + w];
    int g = b * 8 + (c >> 4);
    float nv = (v - mr[g * 2]) * mr[g * 2 + 1] * P[P_GNG + c] + P[P_GNB + c];
    float ge = 0.5f * nv * (1.f + erff(nv * 0.70710678118f));
    acc += ge * P[P_PWW + c];
  }
  float off = acc + P[P_PWB];
  float ofv = tanhf(off) * 8.0f;
  offf[bh * 128 + w] = ofv;
  dout[16777216 + bh * 128 + w] = ofv;
}

// ---------------- K4: y-only grid sample + transpose -> seq f32 (l,c) ------------
__global__ __launch_bounds__(128) void k_deform(const void* __restrict__ x,
                                                const void* __restrict__ gng,
                                                const float* __restrict__ offf,
                                                float* __restrict__ seqc,
                                                int s0) {
  int bh = s0 + blockIdx.x;
  int b = bh >> 7, h = bh & 127;
  int w = threadIdx.x;
  bool f32x = in_is_f32(gng);
  __shared__ float t[128 * 130];
  float ofv = offf[bh * 128 + w];
  float gy = -1.f + (2.f / 127.f) * (float)h + ofv * (2.f / 127.f);
  gy = fminf(fmaxf(gy, -1.f), 1.f);
  float py = (gy + 1.f) * 0.5f * 127.f;
  py = fminf(fmaxf(py, 0.f), 127.f);
  float y0f = floorf(py);
  float wy = py - y0f;
  int y0 = (int)y0f;
  int y1 = min(y0 + 1, 127);
  const float* xfb = (const float*)x + (size_t)b * 128 * 16384;
  const unsigned short* xbb = (const unsigned short*)x + (size_t)b * 128 * 16384;
  for (int c = 0; c < 128; ++c) {
    size_t o0 = (size_t)c * 16384 + y0 * 128 + w;
    size_t o1 = (size_t)c * 16384 + y1 * 128 + w;
    float v0, v1;
    if (f32x) { v0 = xfb[o0]; v1 = xfb[o1]; }
    else      { v0 = b2f(xbb[o0]); v1 = b2f(xbb[o1]); }
    t[c * 130 + w] = v0 + wy * (v1 - v0);
  }
  __syncthreads();
  int c = threadIdx.x;
  float* sp = seqc + (size_t)blockIdx.x * 16384;
  for (int l = 0; l < 128; ++l) sp[l * 128 + c] = t[c * 130 + l];
}

// ---------------- G1: zxbcdt = seq @ wproj^T — LDS-tiled VALU --------------------
__global__ __launch_bounds__(256) void k_gemm1(const float* __restrict__ seqp,
                                               const float* __restrict__ wproj,
                                               const float* __restrict__ P,
                                               float* __restrict__ z,
                                               float* __restrict__ xbc,
                                               float* __restrict__ dtb) {
  __shared__ float As[16 * 129];
  __shared__ float Bs[16 * 129];
  int m0 = blockIdx.x * 16;
  int e0 = blockIdx.y * 16;
  for (int i = threadIdx.x; i < 2048; i += 256) {
    int row = i >> 7, k = i & 127;
    As[row * 129 + k] = seqp[(size_t)(m0 + row) * 128 + k];
    int e = e0 + row;
    Bs[row * 129 + k] = (e < 648) ? wproj[(size_t)e * 128 + k] : 0.f;
  }
  __syncthreads();
  int tx = threadIdx.x & 15;
  int ty = threadIdx.x >> 4;
  float acc = 0.f;
#pragma unroll 8
  for (int k = 0; k < 128; ++k) acc += As[ty * 129 + k] * Bs[tx * 129 + k];
  int m = m0 + ty;
  int e = e0 + tx;
  if (e < 256) {
    z[(size_t)m * 256 + e] = acc;
  } else if (e < 640) {
    xbc[(size_t)m * 384 + (e - 256)] = acc;
  } else if (e < 648) {
    float dv = acc + P[P_DTB + e - 640];
    float sp = (dv > 20.f) ? dv : log1pf(__expf(dv));
    dtb[(size_t)m * 8 + (e - 640)] = sp;
  }
}

// ---------------- K5: causal conv1d + SiLU, out-of-place -------------------------
__global__ __launch_bounds__(256) void k_conv1d_v2(const float* __restrict__ xbc,
                                                   float* __restrict__ pc,
                                                   const float* __restrict__ P) {
  const float* in = xbc + (size_t)blockIdx.x * 49152;   // 128*384
  float* out = pc + (size_t)blockIdx.x * 49152;
  for (int e = threadIdx.x; e < 384; e += 256) {
    float w0 = P[P_CW + e * 4 + 0], w1 = P[P_CW + e * 4 + 1];
    float w2 = P[P_CW + e * 4 + 2], w3 = P[P_CW + e * 4 + 3];
    float bb = P[P_CB + e];
    float x0 = 0.f, x1 = 0.f, x2 = 0.f;
    for (int l = 0; l < 128; ++l) {
      float x3 = in[l * 384 + e];
      float a = bb + w0 * x0 + w1 * x1 + w2 * x2 + w3 * x3;
      out[l * 384 + e] = a / (1.f + __expf(-a));
      x0 = x1; x1 = x2; x2 = x3;
    }
  }
}

// ---------------- K6: selective scan. block=seq; thread=(head,d), 64 states ------
__global__ __launch_bounds__(256) void k_scan_v2(const float* __restrict__ pc,
                                                 const float* __restrict__ dtb,
                                                 const float* __restrict__ P,
                                                 float* __restrict__ ys) {
  int seq = blockIdx.x;
  int head = threadIdx.x >> 5;    // 0..7
  int d = threadIdx.x & 31;       // 0..31
  float A = -__expf(P[P_ALOG + head]);
  float Dk = P[P_DSKIP + head];
  float h[64];
#pragma unroll
  for (int s = 0; s < 64; ++s) h[s] = 0.f;
  __shared__ float sBC[128];      // B[0..63], C[64..127]
  const float* base = pc + (size_t)seq * 49152;
  const float* dtp = dtb + (size_t)seq * 1024;
  float* yp = ys + (size_t)seq * 32768;
  for (int l = 0; l < 128; ++l) {
    const float* rb = base + l * 384;
    if (threadIdx.x < 128) sBC[threadIdx.x] = rb[256 + threadIdx.x];
    __syncthreads();
    float dt = dtp[l * 8 + head];
    float dA = __expf(dt * A);
    float xv = rb[head * 32 + d];
    float coef = dt * xv;
    float acc = 0.f;
#pragma unroll 16
    for (int s = 0; s < 64; ++s) {
      h[s] = h[s] * dA + coef * sBC[s];
      acc += h[s] * sBC[64 + s];
    }
    yp[l * 256 + head * 32 + d] = acc + Dk * xv;
    __syncthreads();
  }
}

// ---------------- K7: gate + RMS norm, block per token ---------------------------
__global__ __launch_bounds__(256) void k_gate_v2(const float* __restrict__ ys,
                                                 const float* __restrict__ z,
                                                 const float* __restrict__ P,
                                                 float* __restrict__ ynorm) {
  int l = blockIdx.x;
  int e = threadIdx.x;
  __shared__ float red[4];
  float yv = ys[(size_t)l * 256 + e];
  float zv = z[(size_t)l * 256 + e];
  float g = zv / (1.f + __expf(-zv));
  float y = yv * g;
  float ss = y * y;
  for (int o = 32; o; o >>= 1) ss += __shfl_down(ss, o, 64);
  if ((threadIdx.x & 63) == 0) red[threadIdx.x >> 6] = ss;
  __syncthreads();
  float tot = red[0] + red[1] + red[2] + red[3];
  float r = rsqrtf(tot * (1.f / 256.f) + 1e-5f);
  ynorm[(size_t)l * 256 + e] = y * r * P[P_NG + e];
}

// ---------------- G2: out GEMM — LDS-tiled VALU, f32 NCHW store ------------------
__global__ __launch_bounds__(256) void k_gemm2(const float* __restrict__ ynorm,
                                               const float* __restrict__ outw,
                                               float* __restrict__ dout,
                                               int tok0) {
  __shared__ float As[16 * 257];
  __shared__ float Bs[16 * 257];
  int c0 = blockIdx.x * 16;
  int t0 = blockIdx.y * 16;
  for (int i = threadIdx.x; i < 4096; i += 256) {
    int row = i >> 8, k = i & 255;
    As[row * 257 + k] = outw[(size_t)(c0 + row) * 256 + k];
    Bs[row * 257 + k] = ynorm[(size_t)(t0 + row) * 256 + k];
  }
  __syncthreads();
  int tx = threadIdx.x & 15;
  int ty = threadIdx.x >> 4;
  float acc = 0.f;
#pragma unroll 8
  for (int k = 0; k < 256; ++k) acc += As[ty * 257 + k] * Bs[tx * 257 + k];
  int cc = c0 + ty;
  int l = tok0 + t0 + tx;
  int b = l >> 14, rem = l & 16383;
  int hh = rem >> 7, ww = rem & 127;
  dout[(((size_t)(b * 128 + cc) * 128 + hh) * 128 + ww)] = acc;
}

extern "C" void kernel_launch(void* const* d_in, const int* in_sizes, int n_in,
                              void* d_out, int out_size, void* d_ws, size_t ws_size,
                              hipStream_t stream) {
  const void* x      = d_in[0];
  const void* dww    = d_in[1];
  const void* gng    = d_in[2];
  const void* gnb    = d_in[3];
  const void* pww    = d_in[4];
  const void* pwb    = d_in[5];
  const void* wproj  = d_in[6];
  const void* cw     = d_in[7];
  const void* cb     = d_in[8];
  const void* dtbias = d_in[9];
  const void* alog   = d_in[10];
  const void* dskip  = d_in[11];
  const void* ng     = d_in[12];
  const void* outw   = d_in[13];
  float* out = (float*)d_out;

  // ws layout (bytes):
  //   0        gst (512)
  //   4096     mr (512)
  //   8192     P (32768)        -> 40960
  //   40960    wprojf (331776)  -> 372736
  //   372736   outwf (131072)   -> 503808
  //   503808   offf (524288)    -> 1028096
  //   1028096  chunk buffers
  char* ws = (char*)d_ws;
  float* gst    = (float*)(ws + 0);
  float* mr     = (float*)(ws + 4096);
  float* P      = (float*)(ws + 8192);
  float* wprojf = (float*)(ws + 40960);
  float* outwf  = (float*)(ws + 372736);
  float* offf   = (float*)(ws + 503808);
  char* cbase   = ws + 1028096;

  // h1 (f32, 67,108,864 B) lives in d_out's out_2d region.
  float* h1f = out;

  // Per-sequence chunk bytes: seq 65536 + z 131072 + xbc 196608 + pc 196608
  //                         + dtb 4096 + ys 131072 + ynorm 131072 = 856064.
  const int opts[11] = {1024, 512, 256, 128, 64, 32, 16, 8, 4, 2, 1};
  int CH = 1;
  for (int i = 0; i < 11; ++i) {
    if (1028096ull + (unsigned long long)opts[i] * 856064ull <= (unsigned long long)ws_size) {
      CH = opts[i];
      break;
    }
  }
  int NC = 1024 / CH;

  float* seqf = (float*)(cbase);
  float* zf   = (float*)(cbase + (size_t)CH * 65536);
  float* xbcf = (float*)(cbase + (size_t)CH * 196608);
  float* pcf  = (float*)(cbase + (size_t)CH * 393216);
  float* dtbf = (float*)(cbase + (size_t)CH * 589824);
  float* ysf  = (float*)(cbase + (size_t)CH * 593920);
  float* ynf  = (float*)(cbase + (size_t)CH * 724992);

  k_prep_params<<<1, 256, 0, stream>>>(dww, cw, cb, gng, gnb, pww, pwb, dtbias,
                                       alog, dskip, ng, P, gst);
  k_prep_w<<<128, 256, 0, stream>>>(wproj, outw, gng, wprojf, outwf);
  k_dwconv<<<1024, 256, 0, stream>>>(x, gng, P, h1f, gst);
  k_stats<<<1, 64, 0, stream>>>(gst, mr);
  k_gn_off<<<1024, 128, 0, stream>>>(h1f, mr, P, offf, out);

  for (int c = 0; c < NC; ++c) {
    int s0 = c * CH;
    k_deform<<<CH, 128, 0, stream>>>(x, gng, offf, seqf, s0);
    k_gemm1<<<dim3(CH * 8, 41), 256, 0, stream>>>(seqf, wprojf, P, zf, xbcf, dtbf);
    k_conv1d_v2<<<CH, 256, 0, stream>>>(xbcf, pcf, P);
    k_scan_v2<<<CH, 256, 0, stream>>>(pcf, dtbf, P, ysf);
    k_gate_v2<<<CH * 128, 256, 0, stream>>>(ysf, zf, P, ynf);
    k_gemm2<<<dim3(8, CH * 8), 256, 0, stream>>>(ynf, outwf, out, s0 * 128);
  }
}